// Round 5
// baseline (297.058 us; speedup 1.0000x reference)
//
#include <hip/hip_runtime.h>
#include <cstddef>

#define H   256
#define L   2048
#define B   32
#define V   50257
#define H2  512
#define H4  1024
#define CH  64                        // flash chunk rows
#define NCH (L/CH)                    // 32 chunks per batch

// output flat offsets (floats)
#define LP_OFF 0
#define HN_OFF (B*V)                 // 1608224
#define CN_OFF (HN_OFF + B*H)        // 1616416
#define AW_OFF (CN_OFF + B*H)        // 1624608

// workspace layout (floats)
#define WS_WP    0                    // 32*256 w partials (k-sliced)
#define WS_XL    (WS_WP + 32*256)     // 32*512: [h_new | attn_applied]
#define WS_S     (WS_XL + B*H2)       // 32*2048 raw scores
#define WS_AV    (WS_S + B*L)         // 1024*256 chunk partial vectors
#define WS_AM    (WS_AV + B*NCH*H)    // 1024 chunk max
#define WS_AZ    (WS_AM + B*NCH)      // 1024 chunk sumexp
#define WS_PM    (WS_AZ + B*NCH)      // 32*400 lsm per-block max
#define WS_PZ    (WS_PM + 12800)      // 32*400 lsm per-block sumexp

#define NBLK_LOG 393                  // ceil(V/128)

typedef __attribute__((ext_vector_type(8))) short bf16x8;
typedef __attribute__((ext_vector_type(4))) float f32x4;

__device__ inline unsigned short f2bf(float f) {
    unsigned u = __builtin_bit_cast(unsigned, f);
    u += 0x7FFFu + ((u >> 16) & 1u);          // RNE to bf16
    return (unsigned short)(u >> 16);
}

// ---------------------------------------------------------------- prep (distributed):
// block p (of 32) handles k-slice [8p, 8p+8): partial[h] = sum v[k]*W_attn[k, H+h]
__global__ __launch_bounds__(256) void k_prep(const float* __restrict__ W_attn,
                                              const float* __restrict__ v,
                                              float* __restrict__ ws) {
    int p = blockIdx.x, t = threadIdx.x;
    const float* base = W_attn + H + t;
    float acc = 0.f;
    #pragma unroll
    for (int kk = 0; kk < 8; kk++) {
        int k = p * 8 + kk;
        acc += v[k] * base[(size_t)k * H2];
    }
    ws[WS_WP + p * 256 + t] = acc;
}

// ---------------------------------------------------------------- flash attention (one enc pass):
// block = (b, chunk of 64 l).  Reduces w partials (L2-hot), then scores with
// k-split-16 (4 rows/wave in parallel, 4 shuffle steps), chunk softmax partial,
// weighted vector partial from L1/L2-hot enc rows.
__global__ __launch_bounds__(256) void k_attn_flash(const float* __restrict__ enc,
                                                    float* __restrict__ ws) {
    int bid = blockIdx.x;             // b*NCH + chunk
    int b = bid >> 5, chunk = bid & (NCH - 1);
    int t = threadIdx.x;
    int wave = t >> 6, lane = t & 63;
    int g = lane >> 4, u = lane & 15;
    __shared__ float w_s[256];
    __shared__ float s_lds[CH];
    __shared__ float p_lds[CH];
    __shared__ float red[CH];
    __shared__ float vec_lds[4][256];

    // combine w partials (same 32 KB for every block -> L2-resident)
    float wsum = 0.f;
    #pragma unroll 8
    for (int p = 0; p < 32; p++) wsum += ws[WS_WP + p * 256 + t];
    w_s[t] = wsum;
    __syncthreads();

    size_t rowbase = (size_t)b * L + chunk * CH;
    const float4* w4s = (const float4*)w_s;
    float4 w0 = w4s[u], w1 = w4s[16 + u], w2 = w4s[32 + u], w3 = w4s[48 + u];

    // phase 1: scores.  wave handles rows [wave*16, wave*16+16), 4 at a time (one per g);
    // 16 lanes (u) split k, 4 independent float4 loads per lane per row.
    #pragma unroll
    for (int ir = 0; ir < 4; ir++) {
        int rl = wave * 16 + ir * 4 + g;
        const float4* e4 = (const float4*)(enc + (rowbase + rl) * H);
        float4 a0 = e4[u], a1 = e4[16 + u], a2 = e4[32 + u], a3 = e4[48 + u];
        float p = a0.x * w0.x + a0.y * w0.y + a0.z * w0.z + a0.w * w0.w
                + a1.x * w1.x + a1.y * w1.y + a1.z * w1.z + a1.w * w1.w
                + a2.x * w2.x + a2.y * w2.y + a2.z * w2.z + a2.w * w2.w
                + a3.x * w3.x + a3.y * w3.y + a3.z * w3.z + a3.w * w3.w;
        p += __shfl_down(p, 8); p += __shfl_down(p, 4);
        p += __shfl_down(p, 2); p += __shfl_down(p, 1);
        if (u == 0) s_lds[rl] = p;
    }
    __syncthreads();

    // chunk softmax partial over 64 rows
    if (t < CH) red[t] = s_lds[t];
    __syncthreads();
    for (int off = 32; off; off >>= 1) { if (t < off) red[t] = fmaxf(red[t], red[t + off]); __syncthreads(); }
    float m = red[0];
    __syncthreads();
    if (t < CH) {
        float e = __expf(s_lds[t] - m);
        p_lds[t] = e; red[t] = e;
        ws[WS_S + rowbase + t] = s_lds[t];
    }
    __syncthreads();
    for (int off = 32; off; off >>= 1) { if (t < off) red[t] += red[t + off]; __syncthreads(); }

    // phase 2: weighted vector partial; wave w covers rows [w*16, w*16+16), lane = h float4
    float4 acc = make_float4(0.f, 0.f, 0.f, 0.f);
    const float4* ebase = (const float4*)(enc + (rowbase + wave * 16) * H);
    #pragma unroll 4
    for (int i = 0; i < 16; i++) {
        float p = p_lds[wave * 16 + i];
        float4 a = ebase[i * 64 + lane];
        acc.x += p * a.x; acc.y += p * a.y; acc.z += p * a.z; acc.w += p * a.w;
    }
    *(float4*)&vec_lds[wave][lane * 4] = acc;
    __syncthreads();
    ws[WS_AV + (size_t)bid * 256 + t] = vec_lds[0][t] + vec_lds[1][t] + vec_lds[2][t] + vec_lds[3][t];
    if (t == 0) { ws[WS_AM + bid] = m; ws[WS_AZ + bid] = red[0]; }
}

// ---------------------------------------------------------------- mid = comb + gates + lstm:
// block = (b, hg of 4).  Phase A: recombine chunk partials (redundant per hg; L2-hot),
// build x=[embed|attn] and hidden in LDS; hg==0 also writes attn_weights + XL attn half.
// Phase B: wave w computes gate-type w, 64 gates (k-split-16, 4-j-parallel).
// Phase C: LSTM pointwise for this block's 64 h.
__global__ __launch_bounds__(256) void k_mid(const int* __restrict__ tokens,
                                             const float* __restrict__ emb,
                                             const float* __restrict__ hidden,
                                             const float* __restrict__ cell,
                                             const float* __restrict__ W_ih, const float* __restrict__ b_ih,
                                             const float* __restrict__ W_hh, const float* __restrict__ b_hh,
                                             float* __restrict__ ws,
                                             float* __restrict__ out) {
    int bid = blockIdx.x;             // b*4 + hg
    int b = bid >> 2, hg = bid & 3;
    int t = threadIdx.x;
    __shared__ float mc[NCH], zc[NCH];
    __shared__ float x_s[H2];         // [embed | attn_applied]
    __shared__ float h_s[H];
    __shared__ float gl[4][64];

    // phase A: combine chunk partials for this b
    if (t < NCH) { mc[t] = ws[WS_AM + b * NCH + t]; zc[t] = ws[WS_AZ + b * NCH + t]; }
    __syncthreads();
    float M = -1e30f;
    #pragma unroll
    for (int c = 0; c < NCH; c++) M = fmaxf(M, mc[c]);
    float Z = 0.f;
    #pragma unroll
    for (int c = 0; c < NCH; c++) Z += zc[c] * __expf(mc[c] - M);
    float inv = 1.f / Z;
    float acc = 0.f;
    #pragma unroll 8
    for (int c = 0; c < NCH; c++) acc += __expf(mc[c] - M) * ws[WS_AV + (size_t)(b * NCH + c) * 256 + t];
    acc *= inv;
    x_s[H + t] = acc;
    int tok = tokens[b];
    x_s[t] = emb[(size_t)tok * H + t];
    h_s[t] = hidden[(size_t)b * H + t];
    if (hg == 0) {
        ws[WS_XL + b * H2 + H + t] = acc;
        #pragma unroll
        for (int j = 0; j < 8; j++) {
            int l = t + 256 * j;
            out[AW_OFF + (size_t)b * L + l] = __expf(ws[WS_S + (size_t)b * L + l] - M) * inv;
        }
    }
    __syncthreads();

    // phase B: gates.  wave = gate type; 64 gates per wave, 4 in parallel (g), k split 16 (u).
    int wave = t >> 6, lane = t & 63, g = lane >> 4, u = lane & 15;
    const float4* xs4 = (const float4*)x_s;   // 128 float4
    const float4* hs4 = (const float4*)h_s;   // 64 float4
    #pragma unroll 2
    for (int ir = 0; ir < 16; ir++) {
        int e = hg * 64 + ir * 4 + g;         // h-pos within gate type, 0..255
        int j = wave * 256 + e;               // row of W_ih / W_hh
        const float4* wi = (const float4*)(W_ih + (size_t)j * H2);
        const float4* wh = (const float4*)(W_hh + (size_t)j * H);
        float p = 0.f;
        #pragma unroll
        for (int q = 0; q < 8; q++) {
            float4 a = wi[u + 16 * q];
            float4 x = xs4[u + 16 * q];
            p += a.x * x.x + a.y * x.y + a.z * x.z + a.w * x.w;
        }
        #pragma unroll
        for (int q = 0; q < 4; q++) {
            float4 a = wh[u + 16 * q];
            float4 x = hs4[u + 16 * q];
            p += a.x * x.x + a.y * x.y + a.z * x.z + a.w * x.w;
        }
        p += __shfl_down(p, 8); p += __shfl_down(p, 4);
        p += __shfl_down(p, 2); p += __shfl_down(p, 1);
        if (u == 0) gl[wave][ir * 4 + g] = p + b_ih[j] + b_hh[j];
    }
    __syncthreads();

    // phase C: LSTM pointwise for h in [hg*64, hg*64+64)
    if (t < 64) {
        int h = hg * 64 + t;
        float ig = gl[0][t], fg = gl[1][t], gg = gl[2][t], og = gl[3][t];
        float c = cell[(size_t)b * H + h];
        float si = 1.f / (1.f + __expf(-ig));
        float sf = 1.f / (1.f + __expf(-fg));
        float so = 1.f / (1.f + __expf(-og));
        float cn = sf * c + si * tanhf(gg);
        float hn = so * tanhf(cn);
        out[HN_OFF + (size_t)b * H + h] = hn;
        out[CN_OFF + (size_t)b * H + h] = cn;
        ws[WS_XL + b * H2 + h] = hn;
    }
}

// ---------------------------------------------------------------- logits (bf16 MFMA):
// C[b,r] = X[b,:].W_out[r,:] + b_out[r].  Block = 128 rows; wave = 32 rows (2 strips
// of 16) x 32 batches (2 n-tiles of 16).  W_out loaded f32->bf16 in-register;
// X staged in LDS as bf16.  Epilogue computes per-block log-softmax partials -> ws.
__global__ __launch_bounds__(256) void k_logits(const float* __restrict__ W_out,
                                                const float* __restrict__ b_out,
                                                float* __restrict__ ws,
                                                float* __restrict__ out) {
    __shared__ unsigned short Xl[32 * 520];   // 33,280 B
    int t = threadIdx.x;
    const float4* xl4 = (const float4*)(ws + WS_XL);
    #pragma unroll
    for (int it = 0; it < 16; it++) {
        int fi = t + 256 * it;                // float4 index over 32x128
        int b = fi >> 7, kq = fi & 127;
        float4 xv = xl4[b * 128 + kq];
        unsigned p0 = (unsigned)f2bf(xv.x) | ((unsigned)f2bf(xv.y) << 16);
        unsigned p1 = (unsigned)f2bf(xv.z) | ((unsigned)f2bf(xv.w) << 16);
        unsigned* dst = (unsigned*)&Xl[b * 520 + kq * 4];
        dst[0] = p0; dst[1] = p1;
    }
    __syncthreads();

    int wave = t >> 6, lane = t & 63, quad = lane >> 4, m = lane & 15;
    int rbase = blockIdx.x * 128 + wave * 32;
    f32x4 zero4 = {0.f, 0.f, 0.f, 0.f};
    f32x4 acc[2][2];
    acc[0][0] = zero4; acc[0][1] = zero4; acc[1][0] = zero4; acc[1][1] = zero4;

    int r0 = rbase + m;
    int r1 = rbase + 16 + m;
    bool v0 = r0 < V, v1 = r1 < V;
    const float* wp0 = W_out + (size_t)r0 * H2 + quad * 8;
    const float* wp1 = W_out + (size_t)r1 * H2 + quad * 8;

    for (int kp = 0; kp < 16; kp++) {
        int k0 = kp * 32;
        bf16x8 a0 = {0,0,0,0,0,0,0,0}, a1 = {0,0,0,0,0,0,0,0};
        if (v0) {
            float4 lo = *(const float4*)(wp0 + k0);
            float4 hi = *(const float4*)(wp0 + k0 + 4);
            a0[0]=(short)f2bf(lo.x); a0[1]=(short)f2bf(lo.y); a0[2]=(short)f2bf(lo.z); a0[3]=(short)f2bf(lo.w);
            a0[4]=(short)f2bf(hi.x); a0[5]=(short)f2bf(hi.y); a0[6]=(short)f2bf(hi.z); a0[7]=(short)f2bf(hi.w);
        }
        if (v1) {
            float4 lo = *(const float4*)(wp1 + k0);
            float4 hi = *(const float4*)(wp1 + k0 + 4);
            a1[0]=(short)f2bf(lo.x); a1[1]=(short)f2bf(lo.y); a1[2]=(short)f2bf(lo.z); a1[3]=(short)f2bf(lo.w);
            a1[4]=(short)f2bf(hi.x); a1[5]=(short)f2bf(hi.y); a1[6]=(short)f2bf(hi.z); a1[7]=(short)f2bf(hi.w);
        }
        bf16x8 b0 = *(bf16x8*)&Xl[(size_t)m * 520 + k0 + quad * 8];
        bf16x8 b1 = *(bf16x8*)&Xl[(size_t)(16 + m) * 520 + k0 + quad * 8];
        acc[0][0] = __builtin_amdgcn_mfma_f32_16x16x32_bf16(a0, b0, acc[0][0], 0, 0, 0);
        acc[0][1] = __builtin_amdgcn_mfma_f32_16x16x32_bf16(a0, b1, acc[0][1], 0, 0, 0);
        acc[1][0] = __builtin_amdgcn_mfma_f32_16x16x32_bf16(a1, b0, acc[1][0], 0, 0, 0);
        acc[1][1] = __builtin_amdgcn_mfma_f32_16x16x32_bf16(a1, b1, acc[1][1], 0, 0, 0);
    }

    // epilogue: bias, store, per-wave softmax partials
    float val[2][2][4];
    #pragma unroll
    for (int s = 0; s < 2; s++) {
        #pragma unroll
        for (int i = 0; i < 4; i++) {
            int rr = rbase + s * 16 + quad * 4 + i;
            float bo = (rr < V) ? b_out[rr] : 0.f;
            #pragma unroll
            for (int nt = 0; nt < 2; nt++) {
                float vv = acc[s][nt][i] + bo;
                if (rr < V) {
                    int bcol = nt * 16 + m;
                    out[(size_t)bcol * V + rr] = vv;
                    val[s][nt][i] = vv;
                } else {
                    val[s][nt][i] = -1e30f;
                }
            }
        }
    }
    float pm[2], pz[2];
    #pragma unroll
    for (int nt = 0; nt < 2; nt++) {
        float mx = -1e30f;
        #pragma unroll
        for (int s = 0; s < 2; s++)
            #pragma unroll
            for (int i = 0; i < 4; i++) mx = fmaxf(mx, val[s][nt][i]);
        float sm = 0.f;
        #pragma unroll
        for (int s = 0; s < 2; s++)
            #pragma unroll
            for (int i = 0; i < 4; i++) sm += __expf(val[s][nt][i] - mx);
        pm[nt] = mx; pz[nt] = sm;
    }
    #pragma unroll
    for (int off = 16; off <= 32; off <<= 1) {
        #pragma unroll
        for (int nt = 0; nt < 2; nt++) {
            float om = __shfl_xor(pm[nt], off);
            float oz = __shfl_xor(pz[nt], off);
            float nm = fmaxf(pm[nt], om);
            pz[nt] = pz[nt] * __expf(pm[nt] - nm) + oz * __expf(om - nm);
            pm[nt] = nm;
        }
    }
    __syncthreads();
    float* red = (float*)Xl;
    if (quad == 0) {
        #pragma unroll
        for (int nt = 0; nt < 2; nt++) {
            red[wave * 32 + nt * 16 + m]       = pm[nt];
            red[128 + wave * 32 + nt * 16 + m] = pz[nt];
        }
    }
    __syncthreads();
    if (t < 32) {
        float mf = -1e30f;
        #pragma unroll
        for (int w = 0; w < 4; w++) mf = fmaxf(mf, red[w * 32 + t]);
        float z = 0.f;
        #pragma unroll
        for (int w = 0; w < 4; w++) z += red[128 + w * 32 + t] * __expf(red[w * 32 + t] - mf);
        ws[WS_PM + t * 400 + blockIdx.x] = mf;
        ws[WS_PZ + t * 400 + blockIdx.x] = z;
    }
}

// ---------------------------------------------------------------- log-softmax finalize
// (combine inlined): block (rb, b) rescans this b's 393 partials (L2-hot), reduces,
// then subtracts M+logZ for its 256 rows.
__global__ __launch_bounds__(256) void k_lsm_final(const float* __restrict__ ws,
                                                   float* __restrict__ out) {
    int b = blockIdx.y, t = threadIdx.x;
    float m = -1e30f, z = 0.f;
    for (int i = t; i < NBLK_LOG; i += 256) {
        float mi = ws[WS_PM + b * 400 + i];
        float zi = ws[WS_PZ + b * 400 + i];
        float nm = fmaxf(m, mi);
        z = z * __expf(m - nm) + zi * __expf(mi - nm);
        m = nm;
    }
    __shared__ float rm[256], rz[256];
    rm[t] = m; rz[t] = z; __syncthreads();
    for (int off = 128; off; off >>= 1) {
        if (t < off) {
            float m2 = rm[t + off], z2 = rz[t + off];
            float nm = fmaxf(rm[t], m2);
            rz[t] = rz[t] * __expf(rm[t] - nm) + z2 * __expf(m2 - nm);
            rm[t] = nm;
        }
        __syncthreads();
    }
    float sub = rm[0] + logf(rz[0]);
    int r = blockIdx.x * 256 + t;
    if (r < V) {
        size_t i = (size_t)b * V + r;
        out[i] = out[i] - sub;
    }
}

extern "C" void kernel_launch(void* const* d_in, const int* in_sizes, int n_in,
                              void* d_out, int out_size, void* d_ws, size_t ws_size,
                              hipStream_t stream) {
    const int*   tokens = (const int*)d_in[0];
    const float* hidden = (const float*)d_in[1];
    const float* cell   = (const float*)d_in[2];
    const float* enc    = (const float*)d_in[3];
    const float* emb    = (const float*)d_in[4];
    const float* W_attn = (const float*)d_in[5];
    const float* v      = (const float*)d_in[7];
    const float* W_ih   = (const float*)d_in[8];
    const float* b_ih   = (const float*)d_in[9];
    const float* W_hh   = (const float*)d_in[10];
    const float* b_hh   = (const float*)d_in[11];
    const float* W_out  = (const float*)d_in[12];
    const float* b_out  = (const float*)d_in[13];
    float* out = (float*)d_out;
    float* ws  = (float*)d_ws;

    k_prep<<<32, 256, 0, stream>>>(W_attn, v, ws);
    k_attn_flash<<<B * NCH, 256, 0, stream>>>(enc, ws);
    k_mid<<<B * 4, 256, 0, stream>>>(tokens, emb, hidden, cell,
                                     W_ih, b_ih, W_hh, b_hh, ws, out);
    k_logits<<<NBLK_LOG, 256, 0, stream>>>(W_out, b_out, ws, out);
    k_lsm_final<<<dim3((V + 255) / 256, B), 256, 0, stream>>>(ws, out);
}

// Round 6
// 289.832 us; speedup vs baseline: 1.0249x; 1.0249x over previous
//
#include <hip/hip_runtime.h>
#include <cstddef>

#define H   256
#define L   2048
#define B   32
#define V   50257
#define H2  512
#define H4  1024
#define CH  64                        // flash chunk rows
#define NCH (L/CH)                    // 32 chunks per batch

// output flat offsets (floats)
#define LP_OFF 0
#define HN_OFF (B*V)                 // 1608224
#define CN_OFF (HN_OFF + B*H)        // 1616416
#define AW_OFF (CN_OFF + B*H)        // 1624608

// workspace layout (floats)
#define WS_WP    0                    // 32*256 w partials (k-sliced)
#define WS_XG    (WS_WP + 32*256)     // 32*512: [embedded | attn_applied]
#define WS_XL    (WS_XG + B*H2)       // 32*512: [h_new | attn_applied]
#define WS_S     (WS_XL + B*H2)       // 32*2048 raw scores
#define WS_AV    (WS_S + B*L)         // 1024*256 chunk partial vectors
#define WS_AM    (WS_AV + B*NCH*H)    // 1024 chunk max
#define WS_AZ    (WS_AM + B*NCH)      // 1024 chunk sumexp
#define WS_GATES (WS_AZ + B*NCH)      // 32*1024
#define WS_PM    (WS_GATES + B*H4)    // 32*400 lsm per-block max
#define WS_PZ    (WS_PM + 12800)      // 32*400 lsm per-block sumexp
#define WS_M     (WS_PZ + 12800)      // 32
#define WS_LZ    (WS_M + 32)          // 32

#define NBLK_LOG 393                  // ceil(V/128)

typedef __attribute__((ext_vector_type(8))) short bf16x8;
typedef __attribute__((ext_vector_type(4))) float f32x4;

__device__ inline unsigned short f2bf(float f) {
    unsigned u = __builtin_bit_cast(unsigned, f);
    u += 0x7FFFu + ((u >> 16) & 1u);          // RNE to bf16
    return (unsigned short)(u >> 16);
}

// ---------------------------------------------------------------- prep (distributed):
// block p (of 32) handles k-slice [8p, 8p+8): partial[h] = sum v[k]*W_attn[k, H+h]
__global__ __launch_bounds__(256) void k_prep(const float* __restrict__ W_attn,
                                              const float* __restrict__ v,
                                              float* __restrict__ ws) {
    int p = blockIdx.x, t = threadIdx.x;
    const float* base = W_attn + H + t;
    float acc = 0.f;
    #pragma unroll
    for (int kk = 0; kk < 8; kk++) {
        int k = p * 8 + kk;
        acc += v[k] * base[(size_t)k * H2];
    }
    ws[WS_WP + p * 256 + t] = acc;
}

// ---------------------------------------------------------------- flash attention (one enc pass):
// block = (b, chunk of 64 l).  Reduces w partials (L2-hot), then scores with
// k-split-16 (4 rows/wave in parallel, 4 shuffle steps), chunk softmax partial,
// weighted vector partial from L1/L2-hot enc rows.
__global__ __launch_bounds__(256) void k_attn_flash(const float* __restrict__ enc,
                                                    float* __restrict__ ws) {
    int bid = blockIdx.x;             // b*NCH + chunk
    int b = bid >> 5, chunk = bid & (NCH - 1);
    int t = threadIdx.x;
    int wave = t >> 6, lane = t & 63;
    int g = lane >> 4, u = lane & 15;
    __shared__ float w_s[256];
    __shared__ float s_lds[CH];
    __shared__ float p_lds[CH];
    __shared__ float red[CH];
    __shared__ float vec_lds[4][256];

    // combine w partials (same 32 KB for every block -> L2-resident)
    float wsum = 0.f;
    #pragma unroll 8
    for (int p = 0; p < 32; p++) wsum += ws[WS_WP + p * 256 + t];
    w_s[t] = wsum;
    __syncthreads();

    size_t rowbase = (size_t)b * L + chunk * CH;
    const float4* w4s = (const float4*)w_s;
    float4 w0 = w4s[u], w1 = w4s[16 + u], w2 = w4s[32 + u], w3 = w4s[48 + u];

    // phase 1: scores.  wave handles rows [wave*16, wave*16+16), 4 at a time (one per g);
    // 16 lanes (u) split k, 4 independent float4 loads per lane per row.
    #pragma unroll
    for (int ir = 0; ir < 4; ir++) {
        int rl = wave * 16 + ir * 4 + g;
        const float4* e4 = (const float4*)(enc + (rowbase + rl) * H);
        float4 a0 = e4[u], a1 = e4[16 + u], a2 = e4[32 + u], a3 = e4[48 + u];
        float p = a0.x * w0.x + a0.y * w0.y + a0.z * w0.z + a0.w * w0.w
                + a1.x * w1.x + a1.y * w1.y + a1.z * w1.z + a1.w * w1.w
                + a2.x * w2.x + a2.y * w2.y + a2.z * w2.z + a2.w * w2.w
                + a3.x * w3.x + a3.y * w3.y + a3.z * w3.z + a3.w * w3.w;
        p += __shfl_down(p, 8); p += __shfl_down(p, 4);
        p += __shfl_down(p, 2); p += __shfl_down(p, 1);
        if (u == 0) s_lds[rl] = p;
    }
    __syncthreads();

    // chunk softmax partial over 64 rows
    if (t < CH) red[t] = s_lds[t];
    __syncthreads();
    for (int off = 32; off; off >>= 1) { if (t < off) red[t] = fmaxf(red[t], red[t + off]); __syncthreads(); }
    float m = red[0];
    __syncthreads();
    if (t < CH) {
        float e = __expf(s_lds[t] - m);
        p_lds[t] = e; red[t] = e;
        ws[WS_S + rowbase + t] = s_lds[t];
    }
    __syncthreads();
    for (int off = 32; off; off >>= 1) { if (t < off) red[t] += red[t + off]; __syncthreads(); }

    // phase 2: weighted vector partial; wave w covers rows [w*16, w*16+16), lane = h float4
    float4 acc = make_float4(0.f, 0.f, 0.f, 0.f);
    const float4* ebase = (const float4*)(enc + (rowbase + wave * 16) * H);
    #pragma unroll 4
    for (int i = 0; i < 16; i++) {
        float p = p_lds[wave * 16 + i];
        float4 a = ebase[i * 64 + lane];
        acc.x += p * a.x; acc.y += p * a.y; acc.z += p * a.z; acc.w += p * a.w;
    }
    *(float4*)&vec_lds[wave][lane * 4] = acc;
    __syncthreads();
    ws[WS_AV + (size_t)bid * 256 + t] = vec_lds[0][t] + vec_lds[1][t] + vec_lds[2][t] + vec_lds[3][t];
    if (t == 0) { ws[WS_AM + bid] = m; ws[WS_AZ + bid] = red[0]; }
}

// ---------------------------------------------------------------- combine chunk partials per b:
// attn_applied = (1/Z) sum_c e^{m_c-M} vec_c;  write attn_weights output; embed gather.
__global__ __launch_bounds__(256) void k_attn_comb(const int* __restrict__ tokens,
                                                   const float* __restrict__ emb,
                                                   float* __restrict__ ws,
                                                   float* __restrict__ out) {
    int b = blockIdx.x, t = threadIdx.x;
    __shared__ float mc[NCH], zc[NCH];
    if (t < NCH) { mc[t] = ws[WS_AM + b * NCH + t]; zc[t] = ws[WS_AZ + b * NCH + t]; }
    __syncthreads();
    float M = -1e30f;
    #pragma unroll
    for (int c = 0; c < NCH; c++) M = fmaxf(M, mc[c]);
    float Z = 0.f;
    #pragma unroll
    for (int c = 0; c < NCH; c++) Z += zc[c] * __expf(mc[c] - M);
    float inv = 1.f / Z;
    float acc = 0.f;
    #pragma unroll 8
    for (int c = 0; c < NCH; c++) acc += __expf(mc[c] - M) * ws[WS_AV + (size_t)(b * NCH + c) * 256 + t];
    acc *= inv;
    ws[WS_XG + b * H2 + H + t] = acc;
    ws[WS_XL + b * H2 + H + t] = acc;
    int tok = tokens[b];
    ws[WS_XG + b * H2 + t] = emb[(size_t)tok * H + t];
    #pragma unroll
    for (int j = 0; j < 8; j++) {
        int l = t + 256 * j;
        out[AW_OFF + (size_t)b * L + l] = __expf(ws[WS_S + (size_t)b * L + l] - M) * inv;
    }
}

// ---------------------------------------------------------------- LSTM gates:
// one wave per (b, j): gates = x @ W_ih^T + b_ih + h @ W_hh^T + b_hh
__global__ __launch_bounds__(256) void k_gates(const float* __restrict__ W_ih, const float* __restrict__ b_ih,
                                               const float* __restrict__ W_hh, const float* __restrict__ b_hh,
                                               const float* __restrict__ hidden, float* __restrict__ ws) {
    int t = threadIdx.x;
    int wave = t >> 6, lane = t & 63;
    int o = blockIdx.x * 4 + wave;        // b*1024 + j
    int b = o >> 10, j = o & 1023;
    const float4* wi = (const float4*)(W_ih + (size_t)j * H2);
    const float4* xg = (const float4*)(ws + WS_XG + (size_t)b * H2);
    float4 a0 = wi[lane * 2], a1 = wi[lane * 2 + 1];
    float4 x0 = xg[lane * 2], x1 = xg[lane * 2 + 1];
    float p = a0.x * x0.x + a0.y * x0.y + a0.z * x0.z + a0.w * x0.w
            + a1.x * x1.x + a1.y * x1.y + a1.z * x1.z + a1.w * x1.w;
    const float4* wh = (const float4*)(W_hh + (size_t)j * H);
    const float4* hp = (const float4*)(hidden + (size_t)b * H);
    float4 a2 = wh[lane], x2 = hp[lane];
    p += a2.x * x2.x + a2.y * x2.y + a2.z * x2.z + a2.w * x2.w;
    #pragma unroll
    for (int off = 32; off; off >>= 1) p += __shfl_down(p, off);
    if (lane == 0) ws[WS_GATES + o] = p + b_ih[j] + b_hh[j];
}

// ---------------------------------------------------------------- LSTM cell pointwise
__global__ __launch_bounds__(256) void k_lstm(const float* __restrict__ cell,
                                              float* __restrict__ ws, float* __restrict__ out) {
    int b = blockIdx.x, t = threadIdx.x;
    const float* g = ws + WS_GATES + (size_t)b * H4;
    float ig = g[t], fg = g[H + t], gg = g[2 * H + t], og = g[3 * H + t];
    float c = cell[(size_t)b * H + t];
    float si = 1.f / (1.f + expf(-ig));
    float sf = 1.f / (1.f + expf(-fg));
    float so = 1.f / (1.f + expf(-og));
    float cn = sf * c + si * tanhf(gg);
    float hn = so * tanhf(cn);
    out[HN_OFF + b * H + t] = hn;
    out[CN_OFF + b * H + t] = cn;
    ws[WS_XL + b * H2 + t] = hn;
}

// ---------------------------------------------------------------- logits (bf16 MFMA):
// C[b,r] = X[b,:].W_out[r,:] + b_out[r].  Block = 128 rows; wave = 32 rows (2 strips
// of 16) x 32 batches (2 n-tiles of 16).  W_out loaded f32->bf16 in-register;
// X staged in LDS as bf16.  Epilogue computes per-block log-softmax partials -> ws.
__global__ __launch_bounds__(256) void k_logits(const float* __restrict__ W_out,
                                                const float* __restrict__ b_out,
                                                float* __restrict__ ws,
                                                float* __restrict__ out) {
    __shared__ unsigned short Xl[32 * 520];   // 33,280 B
    int t = threadIdx.x;
    const float4* xl4 = (const float4*)(ws + WS_XL);
    #pragma unroll
    for (int it = 0; it < 16; it++) {
        int fi = t + 256 * it;                // float4 index over 32x128
        int b = fi >> 7, kq = fi & 127;
        float4 xv = xl4[b * 128 + kq];
        unsigned p0 = (unsigned)f2bf(xv.x) | ((unsigned)f2bf(xv.y) << 16);
        unsigned p1 = (unsigned)f2bf(xv.z) | ((unsigned)f2bf(xv.w) << 16);
        unsigned* dst = (unsigned*)&Xl[b * 520 + kq * 4];
        dst[0] = p0; dst[1] = p1;
    }
    __syncthreads();

    int wave = t >> 6, lane = t & 63, quad = lane >> 4, m = lane & 15;
    int rbase = blockIdx.x * 128 + wave * 32;
    f32x4 zero4 = {0.f, 0.f, 0.f, 0.f};
    f32x4 acc[2][2];
    acc[0][0] = zero4; acc[0][1] = zero4; acc[1][0] = zero4; acc[1][1] = zero4;

    int r0 = rbase + m;
    int r1 = rbase + 16 + m;
    bool v0 = r0 < V, v1 = r1 < V;
    const float* wp0 = W_out + (size_t)r0 * H2 + quad * 8;
    const float* wp1 = W_out + (size_t)r1 * H2 + quad * 8;

    for (int kp = 0; kp < 16; kp++) {
        int k0 = kp * 32;
        bf16x8 a0 = {0,0,0,0,0,0,0,0}, a1 = {0,0,0,0,0,0,0,0};
        if (v0) {
            float4 lo = *(const float4*)(wp0 + k0);
            float4 hi = *(const float4*)(wp0 + k0 + 4);
            a0[0]=(short)f2bf(lo.x); a0[1]=(short)f2bf(lo.y); a0[2]=(short)f2bf(lo.z); a0[3]=(short)f2bf(lo.w);
            a0[4]=(short)f2bf(hi.x); a0[5]=(short)f2bf(hi.y); a0[6]=(short)f2bf(hi.z); a0[7]=(short)f2bf(hi.w);
        }
        if (v1) {
            float4 lo = *(const float4*)(wp1 + k0);
            float4 hi = *(const float4*)(wp1 + k0 + 4);
            a1[0]=(short)f2bf(lo.x); a1[1]=(short)f2bf(lo.y); a1[2]=(short)f2bf(lo.z); a1[3]=(short)f2bf(lo.w);
            a1[4]=(short)f2bf(hi.x); a1[5]=(short)f2bf(hi.y); a1[6]=(short)f2bf(hi.z); a1[7]=(short)f2bf(hi.w);
        }
        bf16x8 b0 = *(bf16x8*)&Xl[(size_t)m * 520 + k0 + quad * 8];
        bf16x8 b1 = *(bf16x8*)&Xl[(size_t)(16 + m) * 520 + k0 + quad * 8];
        acc[0][0] = __builtin_amdgcn_mfma_f32_16x16x32_bf16(a0, b0, acc[0][0], 0, 0, 0);
        acc[0][1] = __builtin_amdgcn_mfma_f32_16x16x32_bf16(a0, b1, acc[0][1], 0, 0, 0);
        acc[1][0] = __builtin_amdgcn_mfma_f32_16x16x32_bf16(a1, b0, acc[1][0], 0, 0, 0);
        acc[1][1] = __builtin_amdgcn_mfma_f32_16x16x32_bf16(a1, b1, acc[1][1], 0, 0, 0);
    }

    // epilogue: bias, store, per-wave softmax partials
    float val[2][2][4];
    #pragma unroll
    for (int s = 0; s < 2; s++) {
        #pragma unroll
        for (int i = 0; i < 4; i++) {
            int rr = rbase + s * 16 + quad * 4 + i;
            float bo = (rr < V) ? b_out[rr] : 0.f;
            #pragma unroll
            for (int nt = 0; nt < 2; nt++) {
                float vv = acc[s][nt][i] + bo;
                if (rr < V) {
                    int bcol = nt * 16 + m;
                    out[(size_t)bcol * V + rr] = vv;
                    val[s][nt][i] = vv;
                } else {
                    val[s][nt][i] = -1e30f;
                }
            }
        }
    }
    float pm[2], pz[2];
    #pragma unroll
    for (int nt = 0; nt < 2; nt++) {
        float mx = -1e30f;
        #pragma unroll
        for (int s = 0; s < 2; s++)
            #pragma unroll
            for (int i = 0; i < 4; i++) mx = fmaxf(mx, val[s][nt][i]);
        float sm = 0.f;
        #pragma unroll
        for (int s = 0; s < 2; s++)
            #pragma unroll
            for (int i = 0; i < 4; i++) sm += __expf(val[s][nt][i] - mx);
        pm[nt] = mx; pz[nt] = sm;
    }
    #pragma unroll
    for (int off = 16; off <= 32; off <<= 1) {
        #pragma unroll
        for (int nt = 0; nt < 2; nt++) {
            float om = __shfl_xor(pm[nt], off);
            float oz = __shfl_xor(pz[nt], off);
            float nm = fmaxf(pm[nt], om);
            pz[nt] = pz[nt] * __expf(pm[nt] - nm) + oz * __expf(om - nm);
            pm[nt] = nm;
        }
    }
    __syncthreads();
    float* red = (float*)Xl;
    if (quad == 0) {
        #pragma unroll
        for (int nt = 0; nt < 2; nt++) {
            red[wave * 32 + nt * 16 + m]       = pm[nt];
            red[128 + wave * 32 + nt * 16 + m] = pz[nt];
        }
    }
    __syncthreads();
    if (t < 32) {
        float mf = -1e30f;
        #pragma unroll
        for (int w = 0; w < 4; w++) mf = fmaxf(mf, red[w * 32 + t]);
        float z = 0.f;
        #pragma unroll
        for (int w = 0; w < 4; w++) z += red[128 + w * 32 + t] * __expf(red[w * 32 + t] - mf);
        ws[WS_PM + t * 400 + blockIdx.x] = mf;
        ws[WS_PZ + t * 400 + blockIdx.x] = z;
    }
}

// ---------------------------------------------------------------- combine log-softmax partials
__global__ __launch_bounds__(256) void k_lsm_comb(float* __restrict__ ws) {
    int b = blockIdx.x, t = threadIdx.x;
    float m = -1e30f, z = 0.f;
    for (int i = t; i < NBLK_LOG; i += 256) {
        float mi = ws[WS_PM + b * 400 + i];
        float zi = ws[WS_PZ + b * 400 + i];
        float nm = fmaxf(m, mi);
        z = z * __expf(m - nm) + zi * __expf(mi - nm);
        m = nm;
    }
    __shared__ float rm[256], rz[256];
    rm[t] = m; rz[t] = z; __syncthreads();
    for (int off = 128; off; off >>= 1) {
        if (t < off) {
            float m2 = rm[t + off], z2 = rz[t + off];
            float nm = fmaxf(rm[t], m2);
            rz[t] = rz[t] * __expf(rm[t] - nm) + z2 * __expf(m2 - nm);
            rm[t] = nm;
        }
        __syncthreads();
    }
    if (t == 0) { ws[WS_M + b] = rm[0]; ws[WS_LZ + b] = logf(rz[0]); }
}

__global__ __launch_bounds__(256) void k_lsm_final(const float* __restrict__ ws, float* __restrict__ out) {
    int b = blockIdx.y;
    int r = blockIdx.x * 256 + threadIdx.x;
    if (r < V) {
        size_t i = (size_t)b * V + r;
        out[i] = out[i] - ws[WS_M + b] - ws[WS_LZ + b];
    }
}

extern "C" void kernel_launch(void* const* d_in, const int* in_sizes, int n_in,
                              void* d_out, int out_size, void* d_ws, size_t ws_size,
                              hipStream_t stream) {
    const int*   tokens = (const int*)d_in[0];
    const float* hidden = (const float*)d_in[1];
    const float* cell   = (const float*)d_in[2];
    const float* enc    = (const float*)d_in[3];
    const float* emb    = (const float*)d_in[4];
    const float* W_attn = (const float*)d_in[5];
    const float* v      = (const float*)d_in[7];
    const float* W_ih   = (const float*)d_in[8];
    const float* b_ih   = (const float*)d_in[9];
    const float* W_hh   = (const float*)d_in[10];
    const float* b_hh   = (const float*)d_in[11];
    const float* W_out  = (const float*)d_in[12];
    const float* b_out  = (const float*)d_in[13];
    float* out = (float*)d_out;
    float* ws  = (float*)d_ws;

    k_prep<<<32, 256, 0, stream>>>(W_attn, v, ws);
    k_attn_flash<<<B * NCH, 256, 0, stream>>>(enc, ws);
    k_attn_comb<<<B, 256, 0, stream>>>(tokens, emb, ws, out);
    k_gates<<<(B * H4) / 4, 256, 0, stream>>>(W_ih, b_ih, W_hh, b_hh, hidden, ws);
    k_lstm<<<B, 256, 0, stream>>>(cell, ws, out);
    k_logits<<<NBLK_LOG, 256, 0, stream>>>(W_out, b_out, ws, out);
    k_lsm_comb<<<B, 256, 0, stream>>>(ws);
    k_lsm_final<<<dim3((V + 255) / 256, B), 256, 0, stream>>>(ws, out);
}